// Round 5
// baseline (236.170 us; speedup 1.0000x reference)
//
#include <hip/hip_runtime.h>
#include <hip/hip_fp16.h>
#include <math.h>
#include <stdint.h>

#define HH 512
#define WW 512
#define NIMG 24
#define CCH 3
#define TAU 0.25f
#define TVEPS 2e-4f
#define NUMEL 262144.0f

// LDS strides for the tv_out recompute path (round-2 verified)
#define LSF 69
#define LSH 70

// ws layout (256 MiB):
//   byte 0     : sc — 2 slots x 128 floats; slot s at sc+128*s:
//                [0..23]=E_prev, [32..55]=E_init, int[64..87]=done, int[96..119]=last_k
//   byte 4096  : sums — float [2][4][NIMG][64]; slot = m&1; arrays 0=da,1=na,2=db,3=nb
//   byte 65536 : imgh (__half, 24*512*512)
//   byte 12648448 : ptA (uint32 packed half2)
//   byte 37814272 : ptB

__device__ __forceinline__ float2 h2f(uint32_t v) {
    __half2 h; *reinterpret_cast<uint32_t*>(&h) = v;
    return __half22float2(h);
}
__device__ __forceinline__ uint32_t f2h2(float a, float b) {
    __half2 h = __floats2half2_rn(a, b);
    return *reinterpret_cast<uint32_t*>(&h);
}
__device__ __forceinline__ void h4_to_f(uint2 hv, float* f) {
    float2 a = h2f(hv.x), b = h2f(hv.y);
    f[0] = a.x; f[1] = a.y; f[2] = b.x; f[3] = b.y;
}

__device__ __forceinline__ int SUMIX(int slot, int arr, int im) {
    return ((slot * 4 + arr) * NIMG + im) * 64;
}

__device__ __forceinline__ void red4_store(float a, float b, float c, float d,
                                           float* pa, float* pb, float* pc, float* pdd,
                                           int tid) {
    for (int off = 32; off > 0; off >>= 1) {
        a += __shfl_down(a, off, 64);
        b += __shfl_down(b, off, 64);
        c += __shfl_down(c, off, 64);
        d += __shfl_down(d, off, 64);
    }
    __shared__ float sr[4][4];
    int wave = tid >> 6, lane = tid & 63;
    if (lane == 0) { sr[0][wave] = a; sr[1][wave] = b; sr[2][wave] = c; sr[3][wave] = d; }
    __syncthreads();
    if (tid == 0) {
        *pa = (sr[0][0] + sr[0][1]) + (sr[0][2] + sr[0][3]);
        *pb = (sr[1][0] + sr[1][1]) + (sr[1][2] + sr[1][3]);
        *pc = (sr[2][0] + sr[2][1]) + (sr[2][2] + sr[2][3]);
        *pdd = (sr[3][0] + sr[3][1]) + (sr[3][2] + sr[3][3]);
    }
}

// ---------- LDS helpers used ONLY by tv_out's even-k recompute (round-2 verified) ----------
struct Smem {
    uint32_t PT[68 * LSF];
    float    OA[68 * LSF];
    __half   IM[68 * LSH];
};

__device__ void stage_pt_im(Smem& S, const uint32_t* __restrict__ ptg,
                            const __half* __restrict__ hI,
                            int x0, int y0, int tid) {
    for (int idx = tid; idx < 68 * 34; idx += 256) {
        int r = idx / 34, mq = idx - r * 34;
        int c = 2 * mq;
        int y = y0 - 2 + r, x = x0 - 2 + c;
        uint2 pv = make_uint2(0u, 0u);
        uint32_t iv = 0u;
        if ((unsigned)y < (unsigned)HH && (unsigned)x < (unsigned)WW) {
            size_t off = (size_t)y * WW + x;
            pv = *(const uint2*)(ptg + off);
            iv = *(const uint32_t*)(hI + off);
        }
        S.PT[r * LSF + c] = pv.x;
        S.PT[r * LSF + c + 1] = pv.y;
        *(uint32_t*)&S.IM[r * LSH + c] = iv;
    }
}

__device__ void phase_outA_x(Smem& S, int tid) {
    for (int idx = tid; idx < 67 * 67; idx += 256) {
        int r = idx / 67, c = idx - r * 67;
        r += 1; c += 1;
        float2 cf = h2f(S.PT[r * LSF + c]);
        float up = h2f(S.PT[(r - 1) * LSF + c]).x;
        float lf = h2f(S.PT[r * LSF + c - 1]).y;
        float im = __half2float(S.IM[r * LSH + c]);
        S.OA[r * LSF + c] = im + (-(cf.x + cf.y) + up + lf);
    }
}

__device__ void phase_ptA_x(Smem& S, int x0, int y0, int tid, float tw) {
    for (int idx = tid; idx < 66 * 66; idx += 256) {
        int r = idx / 66, c = idx - r * 66;
        r += 1; c += 1;
        int y = y0 - 2 + r, x = x0 - 2 + c;
        if ((unsigned)y < (unsigned)HH && (unsigned)x < (unsigned)WW) {
            float o = S.OA[r * LSF + c];
            float g0 = (y < HH - 1) ? S.OA[(r + 1) * LSF + c] - o : 0.f;
            float g1 = (x < WW - 1) ? S.OA[r * LSF + c + 1] - o : 0.f;
            float ss2 = g0 * g0 + g1 * g1;
            float nrm = (ss2 > 0.f) ? sqrtf(ss2) : 0.f;
            float inv = __builtin_amdgcn_rcpf(1.f + tw * nrm);
            float2 cf = h2f(S.PT[r * LSF + c]);
            S.PT[r * LSF + c] = f2h2((cf.x - TAU * g0) * inv, (cf.y - TAU * g1) * inv);
        } else {
            S.PT[r * LSF + c] = 0u;
        }
    }
}

// =========================== iteration 0 (round-4 verified) ===========================
__global__ __launch_bounds__(256, 4) void tv_step0(
    const float* __restrict__ img, const float* __restrict__ weight,
    __half* __restrict__ imgh, uint32_t* __restrict__ ptout,
    float* __restrict__ pn0)
{
    const int im = blockIdx.z;
    const int bid = blockIdx.y * 8 + blockIdx.x;
    const float w = weight[im / CCH];
    const int x0 = blockIdx.x * 64, y0 = blockIdx.y * 64;
    const float* imgI = img + (size_t)im * HH * WW;
    __half* hI = imgh + (size_t)im * HH * WW;
    uint32_t* pI = ptout + (size_t)im * HH * WW;
    __shared__ float s[65][68];
    const int tid = threadIdx.x;
    const int tx = tid & 15, ry = tid >> 4;
    const int gx = x0 + 4 * tx;

    float o[4][4];
    #pragma unroll
    for (int i = 0; i < 4; ++i) {
        int ey = ry + 16 * i, gy = y0 + ey;
        float4 v = *(const float4*)(imgI + (size_t)gy * WW + gx);
        o[i][0] = v.x; o[i][1] = v.y; o[i][2] = v.z; o[i][3] = v.w;
        *(float4*)&s[ey][4 * tx] = v;
    }
    if (tx == 15 && x0 + 64 < WW) {
        #pragma unroll
        for (int i = 0; i < 4; ++i) {
            int ey = ry + 16 * i, gy = y0 + ey;
            s[ey][64] = imgI[(size_t)gy * WW + x0 + 64];
        }
    }
    if (ry == 0 && y0 + 64 < HH) {
        *(float4*)&s[64][4 * tx] = *(const float4*)(imgI + (size_t)(y0 + 64) * WW + gx);
    }
    __syncthreads();

    float accn = 0.f;
    const float tw = TAU / w;
    #pragma unroll
    for (int i = 0; i < 4; ++i) {
        int ey = ry + 16 * i, gy = y0 + ey;
        float4 dn = *(float4*)&s[ey + 1][4 * tx];
        float rt_sh = __shfl_down(o[i][0], 1, 64);
        float rt = (tx == 15) ? s[ey][64] : rt_sh;
        float dnv[4] = {dn.x, dn.y, dn.z, dn.w};
        uint32_t pv[4];
        #pragma unroll
        for (int j = 0; j < 4; ++j) {
            float ov = o[i][j];
            float g0 = (gy < HH - 1) ? dnv[j] - ov : 0.f;
            float rn = (j < 3) ? o[i][j + 1] : rt;
            float g1 = (gx + j < WW - 1) ? rn - ov : 0.f;
            float ss2 = g0 * g0 + g1 * g1;
            float nrm = (ss2 > 0.f) ? sqrtf(ss2) : 0.f;
            accn += nrm;
            float inv = __builtin_amdgcn_rcpf(1.f + tw * nrm);
            pv[j] = f2h2(-TAU * g0 * inv, -TAU * g1 * inv);
        }
        size_t off = (size_t)gy * WW + gx;
        *(uint4*)(pI + off) = make_uint4(pv[0], pv[1], pv[2], pv[3]);
        *(uint2*)(hI + off) = make_uint2(f2h2(o[i][0], o[i][1]), f2h2(o[i][2], o[i][3]));
    }
    for (int off = 32; off > 0; off >>= 1) accn += __shfl_down(accn, off, 64);
    __shared__ float sr[4];
    if ((tid & 63) == 0) sr[tid >> 6] = accn;
    __syncthreads();
    if (tid == 0) pn0[im * 64 + bid] = (sr[0] + sr[1]) + (sr[2] + sr[3]);
}

// ============ fused pair (iterations 2m-1, 2m), register-tile version ============
__global__ __launch_bounds__(256, 2) void tv_fused(
    int m,
    const __half* __restrict__ imgh, const float* __restrict__ weight,
    const uint32_t* __restrict__ pt_in, uint32_t* __restrict__ pt_out,
    float* __restrict__ sc, float* __restrict__ sums)
{
    const int im = blockIdx.z;
    const int bid = blockIdx.y * 8 + blockIdx.x;
    const int tid = threadIdx.x;
    const float w = weight[im / CCH];

    // --- replay head (round-2 verified verbatim) ---
    __shared__ int sh_done;
    {
        const int sIn = (m - 1) & 1;
        if (tid < 64) {
            float da = 0.f, na = 0.f, db = 0.f, nb = 0.f;
            if (m == 1) {
                na = sums[SUMIX(0, 1, im) + tid];
            } else {
                da = sums[SUMIX(sIn, 0, im) + tid];
                na = sums[SUMIX(sIn, 1, im) + tid];
                db = sums[SUMIX(sIn, 2, im) + tid];
                nb = sums[SUMIX(sIn, 3, im) + tid];
            }
            for (int off = 32; off > 0; off >>= 1) {
                da += __shfl_down(da, off, 64);
                na += __shfl_down(na, off, 64);
                db += __shfl_down(db, off, 64);
                nb += __shfl_down(nb, off, 64);
            }
            if (tid == 0) {
                float Eprev, Einit; int done, lastk;
                if (m == 1) {
                    float E0 = w * na / NUMEL;
                    Eprev = E0; Einit = E0; done = 0; lastk = 0;
                } else {
                    const float* sI = sc + sIn * 128;
                    Eprev = sI[im]; Einit = sI[32 + im];
                    done = ((const int*)sI)[64 + im];
                    lastk = ((const int*)sI)[96 + im];
                    if (!done) {
                        float Et = (da + w * na) / NUMEL;
                        if (fabsf(Eprev - Et) < TVEPS * Einit) { done = 1; lastk = 2 * m - 3; }
                        else {
                            Eprev = Et;
                            Et = (db + w * nb) / NUMEL;
                            if (fabsf(Eprev - Et) < TVEPS * Einit) { done = 1; lastk = 2 * m - 2; }
                            else Eprev = Et;
                        }
                    }
                }
                if (bid == 0) {
                    float* sO = sc + (m & 1) * 128;
                    sO[im] = Eprev; sO[32 + im] = Einit;
                    ((int*)sO)[64 + im] = done;
                    ((int*)sO)[96 + im] = lastk;
                }
                sh_done = done;
            }
        }
    }
    __syncthreads();
    if (sh_done) return;

    const int x0 = blockIdx.x * 64, y0 = blockIdx.y * 64;
    const float tw = TAU / w;
    const uint32_t* pinI = pt_in + (size_t)im * HH * WW;
    uint32_t* poutI = pt_out + (size_t)im * HH * WW;
    const __half* hI = imgh + (size_t)im * HH * WW;

    const int tx = tid & 15, ty = tid >> 4;
    const int gx = x0 + 4 * tx, gy0 = y0 + 4 * ty;
    const bool hasN = y0 > 0, hasW = x0 > 0;
    const bool hasS = y0 + 64 < HH, hasE = x0 + 64 < WW;

    __shared__ uint4  XB[16][16];   // band pt rows (pt_in row3 -> pt_a row3)
    __shared__ float4 OB[16][16];   // band out rows (out_a row0 -> out_b row0)
    __shared__ float  WO[17];       // out_a(y0+4k, x0-1)
    __shared__ float  EO[17];       // out_a(y0+4k, x0+64)
    __shared__ uint32_t EP[16];     // pt_a(gy0+3, x0+64) per band

    // ---- stage: owned pt_in + imgh ----
    uint4 c[4]; uint2 ih[4];
    #pragma unroll
    for (int i = 0; i < 4; ++i) {
        size_t off = (size_t)(gy0 + i) * WW + gx;
        c[i] = *(const uint4*)(pinI + off);
        ih[i] = *(const uint2*)(hI + off);
    }
    XB[ty][tx] = c[3];

    // ---- halo loads (edge threads) ----
    uint4 png0 = make_uint4(0u,0u,0u,0u), png1 = make_uint4(0u,0u,0u,0u);
    uint2 ihN = make_uint2(0u, 0u);
    if (ty == 0 && hasN) {
        png0 = *(const uint4*)(pinI + (size_t)(y0 - 2) * WW + gx);
        png1 = *(const uint4*)(pinI + (size_t)(y0 - 1) * WW + gx);
        ihN  = *(const uint2*)(hI + (size_t)(y0 - 1) * WW + gx);
    }
    uint32_t wp1[4] = {0u,0u,0u,0u}, wp2[4] = {0u,0u,0u,0u}, wup = 0u;
    float ihW[4] = {0.f,0.f,0.f,0.f};
    uint32_t wnp1 = 0u;
    if (tx == 0 && hasW) {
        #pragma unroll
        for (int i = 0; i < 4; ++i) {
            wp1[i] = pinI[(size_t)(gy0 + i) * WW + x0 - 1];
            wp2[i] = pinI[(size_t)(gy0 + i) * WW + x0 - 2];
            ihW[i] = __half2float(hI[(size_t)(gy0 + i) * WW + x0 - 1]);
        }
        if (gy0 > 0) wup = pinI[(size_t)(gy0 - 1) * WW + x0 - 1];
        if (ty == 0 && hasN) wnp1 = pinI[(size_t)(y0 - 1) * WW + x0 - 1];
    }
    uint32_t ep1[4] = {0u,0u,0u,0u}, ep2[4] = {0u,0u,0u,0u}, epu1 = 0u, epu2 = 0u;
    float ihE1[4] = {0.f,0.f,0.f,0.f}, ihE2[4] = {0.f,0.f,0.f,0.f};
    uint32_t nep1 = 0u, nep2 = 0u, nepu1 = 0u, nepu2 = 0u;
    float ihNE1 = 0.f, ihNE2 = 0.f;
    if (tx == 15 && hasE) {
        const int xe = x0 + 64;
        #pragma unroll
        for (int i = 0; i < 4; ++i) {
            ep1[i] = pinI[(size_t)(gy0 + i) * WW + xe];
            ep2[i] = pinI[(size_t)(gy0 + i) * WW + xe + 1];
            ihE1[i] = __half2float(hI[(size_t)(gy0 + i) * WW + xe]);
            ihE2[i] = __half2float(hI[(size_t)(gy0 + i) * WW + xe + 1]);
        }
        if (gy0 > 0) {
            epu1 = pinI[(size_t)(gy0 - 1) * WW + xe];
            epu2 = pinI[(size_t)(gy0 - 1) * WW + xe + 1];
        }
        if (ty == 0 && hasN) {
            nep1 = pinI[(size_t)(y0 - 1) * WW + xe];
            nep2 = pinI[(size_t)(y0 - 1) * WW + xe + 1];
            nepu1 = pinI[(size_t)(y0 - 2) * WW + xe];
            nepu2 = pinI[(size_t)(y0 - 2) * WW + xe + 1];
            ihNE1 = __half2float(hI[(size_t)(y0 - 1) * WW + xe]);
            ihNE2 = __half2float(hI[(size_t)(y0 - 1) * WW + xe + 1]);
        }
    }
    uint4 sp1 = make_uint4(0u,0u,0u,0u), sp2 = make_uint4(0u,0u,0u,0u);
    uint2 ihS1 = make_uint2(0u,0u), ihS2 = make_uint2(0u,0u);
    uint32_t wsp1 = 0u, wsp2 = 0u, wsl1 = 0u, wsl2 = 0u;
    float ihSW1 = 0.f, ihSW2 = 0.f;
    uint32_t sep = 0u; float ihSE = 0.f;
    if (ty == 15 && hasS) {
        sp1 = *(const uint4*)(pinI + (size_t)(y0 + 64) * WW + gx);
        sp2 = *(const uint4*)(pinI + (size_t)(y0 + 65) * WW + gx);
        ihS1 = *(const uint2*)(hI + (size_t)(y0 + 64) * WW + gx);
        ihS2 = *(const uint2*)(hI + (size_t)(y0 + 65) * WW + gx);
        if (tx == 0 && hasW) {
            wsp1 = pinI[(size_t)(y0 + 64) * WW + x0 - 1];
            wsp2 = pinI[(size_t)(y0 + 65) * WW + x0 - 1];
            wsl1 = pinI[(size_t)(y0 + 64) * WW + x0 - 2];
            wsl2 = pinI[(size_t)(y0 + 65) * WW + x0 - 2];
            ihSW1 = __half2float(hI[(size_t)(y0 + 64) * WW + x0 - 1]);
            ihSW2 = __half2float(hI[(size_t)(y0 + 65) * WW + x0 - 1]);
        }
        if (tx == 15 && hasE) {
            sep = pinI[(size_t)(y0 + 64) * WW + x0 + 64];
            ihSE = __half2float(hI[(size_t)(y0 + 64) * WW + x0 + 64]);
        }
    }
    __syncthreads();  // s1: XB (pt_in bands) visible

    // ================= OUT_A =================
    float o[4][4];
    float accda = 0.f;
    {
        uint4 up4 = (ty > 0) ? XB[ty - 1][tx] : png1;
        uint32_t ua[4] = {up4.x, up4.y, up4.z, up4.w};
        #pragma unroll
        for (int i = 0; i < 4; ++i) {
            uint32_t ca[4] = {c[i].x, c[i].y, c[i].z, c[i].w};
            uint32_t pr[4] = {c[i].x, c[i].y, c[i].z, c[i].w};
            uint32_t lsh = __shfl_up(c[i].w, 1, 64);
            uint32_t lw = (tx > 0) ? lsh : wp1[i];
            uint32_t cu[4] = {(i > 0) ? (&c[i-1].x)[0] : ua[0],
                              (i > 0) ? (&c[i-1].x)[1] : ua[1],
                              (i > 0) ? (&c[i-1].x)[2] : ua[2],
                              (i > 0) ? (&c[i-1].x)[3] : ua[3]};
            float imv[4]; h4_to_f(ih[i], imv);
            #pragma unroll
            for (int j = 0; j < 4; ++j) {
                float2 cf = h2f(ca[j]);
                float up = h2f(cu[j]).x;
                float le = (j > 0) ? h2f(pr[j - 1]).y : h2f(lw).y;
                float dv = -(cf.x + cf.y) + up + le;
                o[i][j] = imv[j] + dv;
                accda += dv * dv;
            }
        }
    }
    // halo out_a (values default 0; only used when the matching has* is true or masked)
    float oN[4] = {0.f,0.f,0.f,0.f};
    if (ty == 0) {
        uint32_t pga[4] = {png1.x, png1.y, png1.z, png1.w};
        uint32_t p0a[4] = {png0.x, png0.y, png0.z, png0.w};
        uint32_t nsh = __shfl_up(png1.w, 1, 64);
        uint32_t nlw = (tx > 0) ? nsh : wnp1;
        float imn[4]; h4_to_f(ihN, imn);
        #pragma unroll
        for (int j = 0; j < 4; ++j) {
            float2 cf = h2f(pga[j]);
            float up = h2f(p0a[j]).x;
            float le = (j > 0) ? h2f(pga[j - 1]).y : h2f(nlw).y;
            oN[j] = imn[j] + (-(cf.x + cf.y) + up + le);
        }
    }
    float oW[4] = {0.f,0.f,0.f,0.f};
    if (tx == 0) {
        #pragma unroll
        for (int i = 0; i < 4; ++i) {
            float2 cf = h2f(wp1[i]);
            float up = (i > 0) ? h2f(wp1[i - 1]).x : h2f(wup).x;
            float le = h2f(wp2[i]).y;
            oW[i] = ihW[i] + (-(cf.x + cf.y) + up + le);
        }
    }
    float oE1[4] = {0.f,0.f,0.f,0.f}, oE2[4] = {0.f,0.f,0.f,0.f};
    if (tx == 15) {
        #pragma unroll
        for (int i = 0; i < 4; ++i) {
            float2 cf = h2f(ep1[i]);
            float up = (i > 0) ? h2f(ep1[i - 1]).x : h2f(epu1).x;
            float le = h2f(c[i].w).y;
            oE1[i] = ihE1[i] + (-(cf.x + cf.y) + up + le);
            float2 cg = h2f(ep2[i]);
            float up2 = (i > 0) ? h2f(ep2[i - 1]).x : h2f(epu2).x;
            float le2 = h2f(ep1[i]).y;
            oE2[i] = ihE2[i] + (-(cg.x + cg.y) + up2 + le2);
        }
    }
    float oNE1 = 0.f, oNE2 = 0.f;
    if (tx == 15 && ty == 0) {
        float2 cf = h2f(nep1);
        oNE1 = ihNE1 + (-(cf.x + cf.y) + h2f(nepu1).x + h2f(png1.w).y);
        float2 cg = h2f(nep2);
        oNE2 = ihNE2 + (-(cg.x + cg.y) + h2f(nepu2).x + h2f(nep1).y);
    }
    float oS1[4] = {0.f,0.f,0.f,0.f}, oS2[4] = {0.f,0.f,0.f,0.f};
    if (ty == 15) {
        uint32_t s1a[4] = {sp1.x, sp1.y, sp1.z, sp1.w};
        uint32_t s2a[4] = {sp2.x, sp2.y, sp2.z, sp2.w};
        uint32_t c3a[4] = {c[3].x, c[3].y, c[3].z, c[3].w};
        uint32_t s1sh = __shfl_up(sp1.w, 1, 64);
        uint32_t s2sh = __shfl_up(sp2.w, 1, 64);
        uint32_t s1l = (tx > 0) ? s1sh : wsp1;
        uint32_t s2l = (tx > 0) ? s2sh : wsp2;
        float im1[4]; h4_to_f(ihS1, im1);
        float im2[4]; h4_to_f(ihS2, im2);
        #pragma unroll
        for (int j = 0; j < 4; ++j) {
            float2 cf = h2f(s1a[j]);
            float up = h2f(c3a[j]).x;
            float le = (j > 0) ? h2f(s1a[j - 1]).y : h2f(s1l).y;
            oS1[j] = im1[j] + (-(cf.x + cf.y) + up + le);
            float2 cg = h2f(s2a[j]);
            float up2 = h2f(s1a[j]).x;
            float le2 = (j > 0) ? h2f(s2a[j - 1]).y : h2f(s2l).y;
            oS2[j] = im2[j] + (-(cg.x + cg.y) + up2 + le2);
        }
    }
    float oSW1 = 0.f, oSW2 = 0.f;
    if (tx == 0 && ty == 15) {
        float2 cf = h2f(wsp1);
        oSW1 = ihSW1 + (-(cf.x + cf.y) + h2f(wp1[3]).x + h2f(wsl1).y);
        float2 cg = h2f(wsp2);
        oSW2 = ihSW2 + (-(cg.x + cg.y) + h2f(wsp1).x + h2f(wsl2).y);
    }
    float oSE = 0.f;
    if (tx == 15 && ty == 15) {
        float2 cf = h2f(sep);
        oSE = ihSE + (-(cf.x + cf.y) + h2f(ep1[3]).x + h2f(sp1.w).y);
    }

    OB[ty][tx] = make_float4(o[0][0], o[0][1], o[0][2], o[0][3]);
    if (tx == 0) WO[ty] = oW[0];
    if (tx == 0 && ty == 15) WO[16] = oSW1;
    if (tx == 15) EO[ty] = oE1[0];
    if (tx == 15 && ty == 15) EO[16] = oSE;
    __syncthreads();  // s2: OB/WO/EO (out_a bands)

    // ================= PT_A =================
    uint32_t pa[4][4];
    float accna = 0.f;
    {
        float bel4[4];
        if (ty < 15) {
            float4 t = OB[ty + 1][tx];
            bel4[0] = t.x; bel4[1] = t.y; bel4[2] = t.z; bel4[3] = t.w;
        } else {
            bel4[0] = oS1[0]; bel4[1] = oS1[1]; bel4[2] = oS1[2]; bel4[3] = oS1[3];
        }
        #pragma unroll
        for (int i = 0; i < 4; ++i) {
            int gy = gy0 + i;
            float rsh = __shfl_down(o[i][0], 1, 64);
            float rt = (tx < 15) ? rsh : oE1[i];
            uint32_t ca[4] = {c[i].x, c[i].y, c[i].z, c[i].w};
            #pragma unroll
            for (int j = 0; j < 4; ++j) {
                float ov = o[i][j];
                float bel = (i < 3) ? o[i + 1][j] : bel4[j];
                float g0 = (gy < HH - 1) ? bel - ov : 0.f;
                float rn = (j < 3) ? o[i][j + 1] : rt;
                float g1 = (gx + j < WW - 1) ? rn - ov : 0.f;
                float ss2 = g0 * g0 + g1 * g1;
                float nrm = (ss2 > 0.f) ? sqrtf(ss2) : 0.f;
                accna += nrm;
                float inv = __builtin_amdgcn_rcpf(1.f + tw * nrm);
                float2 cf = h2f(ca[j]);
                pa[i][j] = f2h2((cf.x - TAU * g0) * inv, (cf.y - TAU * g1) * inv);
            }
        }
    }
    uint32_t paN[4] = {0u,0u,0u,0u};
    if (ty == 0 && hasN) {
        uint32_t pga[4] = {png1.x, png1.y, png1.z, png1.w};
        float rsh = __shfl_down(oN[0], 1, 64);
        #pragma unroll
        for (int j = 0; j < 4; ++j) {
            float ov = oN[j];
            float g0 = o[0][j] - ov;                       // y = y0-1 < HH-1 always
            float rn = (j < 3) ? oN[j + 1] : ((tx < 15) ? rsh : oNE1);
            float g1 = (gx + j < WW - 1) ? rn - ov : 0.f;
            float ss2 = g0 * g0 + g1 * g1;
            float nrm = (ss2 > 0.f) ? sqrtf(ss2) : 0.f;
            float inv = __builtin_amdgcn_rcpf(1.f + tw * nrm);
            float2 cf = h2f(pga[j]);
            paN[j] = f2h2((cf.x - TAU * g0) * inv, (cf.y - TAU * g1) * inv);
        }
    }
    uint32_t paW[4] = {0u,0u,0u,0u};
    if (tx == 0 && hasW) {
        #pragma unroll
        for (int i = 0; i < 4; ++i) {
            int gy = gy0 + i;
            float ov = oW[i];
            float bel = (i < 3) ? oW[i + 1] : WO[ty + 1];
            float g0 = (gy < HH - 1) ? bel - ov : 0.f;
            float g1 = o[i][0] - ov;                       // x = x0-1 < WW-1 always
            float ss2 = g0 * g0 + g1 * g1;
            float nrm = (ss2 > 0.f) ? sqrtf(ss2) : 0.f;
            float inv = __builtin_amdgcn_rcpf(1.f + tw * nrm);
            float2 cf = h2f(wp1[i]);
            paW[i] = f2h2((cf.x - TAU * g0) * inv, (cf.y - TAU * g1) * inv);
        }
    }
    uint32_t paS[4] = {0u,0u,0u,0u};
    if (ty == 15 && hasS) {
        uint32_t s1a[4] = {sp1.x, sp1.y, sp1.z, sp1.w};
        float rsh = __shfl_down(oS1[0], 1, 64);
        #pragma unroll
        for (int j = 0; j < 4; ++j) {
            float ov = oS1[j];
            float g0 = oS2[j] - ov;                        // y = y0+64 < HH-1 when hasS
            float rn = (j < 3) ? oS1[j + 1] : ((tx < 15) ? rsh : oSE);
            float g1 = (gx + j < WW - 1) ? rn - ov : 0.f;
            float ss2 = g0 * g0 + g1 * g1;
            float nrm = (ss2 > 0.f) ? sqrtf(ss2) : 0.f;
            float inv = __builtin_amdgcn_rcpf(1.f + tw * nrm);
            float2 cf = h2f(s1a[j]);
            paS[j] = f2h2((cf.x - TAU * g0) * inv, (cf.y - TAU * g1) * inv);
        }
    }
    uint32_t paE[4] = {0u,0u,0u,0u};
    if (tx == 15 && hasE) {
        #pragma unroll
        for (int i = 0; i < 4; ++i) {
            int gy = gy0 + i;
            float ov = oE1[i];
            float bel = (i < 3) ? oE1[i + 1] : EO[ty + 1];
            float g0 = (gy < HH - 1) ? bel - ov : 0.f;
            float g1 = oE2[i] - ov;                        // x = x0+64 < WW-1 when hasE
            float ss2 = g0 * g0 + g1 * g1;
            float nrm = (ss2 > 0.f) ? sqrtf(ss2) : 0.f;
            float inv = __builtin_amdgcn_rcpf(1.f + tw * nrm);
            float2 cf = h2f(ep1[i]);
            paE[i] = f2h2((cf.x - TAU * g0) * inv, (cf.y - TAU * g1) * inv);
        }
    }
    uint32_t paNE = 0u;
    if (tx == 15 && ty == 0 && hasN && hasE) {
        float ov = oNE1;
        float g0 = oE1[0] - ov;
        float g1 = oNE2 - ov;
        float ss2 = g0 * g0 + g1 * g1;
        float nrm = (ss2 > 0.f) ? sqrtf(ss2) : 0.f;
        float inv = __builtin_amdgcn_rcpf(1.f + tw * nrm);
        float2 cf = h2f(nep1);
        paNE = f2h2((cf.x - TAU * g0) * inv, (cf.y - TAU * g1) * inv);
    }
    uint32_t paSW = 0u;
    if (tx == 0 && ty == 15 && hasS && hasW) {
        float ov = oSW1;
        float g0 = oSW2 - ov;
        float g1 = oS1[0] - ov;
        float ss2 = g0 * g0 + g1 * g1;
        float nrm = (ss2 > 0.f) ? sqrtf(ss2) : 0.f;
        float inv = __builtin_amdgcn_rcpf(1.f + tw * nrm);
        float2 cf = h2f(wsp1);
        paSW = f2h2((cf.x - TAU * g0) * inv, (cf.y - TAU * g1) * inv);
    }
    XB[ty][tx] = make_uint4(pa[3][0], pa[3][1], pa[3][2], pa[3][3]);
    if (tx == 15) EP[ty] = paE[3];
    __syncthreads();  // s3: XB (pt_a bands), EP

    // ================= OUT_B =================
    float ob[4][4];
    float accdb = 0.f;
    {
        uint4 up4 = (ty > 0) ? XB[ty - 1][tx] : make_uint4(paN[0], paN[1], paN[2], paN[3]);
        uint32_t ua[4] = {up4.x, up4.y, up4.z, up4.w};
        #pragma unroll
        for (int i = 0; i < 4; ++i) {
            uint32_t lsh = __shfl_up(pa[i][3], 1, 64);
            uint32_t lw = (tx > 0) ? lsh : paW[i];
            float imv[4]; h4_to_f(ih[i], imv);
            #pragma unroll
            for (int j = 0; j < 4; ++j) {
                float2 cf = h2f(pa[i][j]);
                float up = (i > 0) ? h2f(pa[i - 1][j]).x : h2f(ua[j]).x;
                float le = (j > 0) ? h2f(pa[i][j - 1]).y : h2f(lw).y;
                float dv = -(cf.x + cf.y) + up + le;
                ob[i][j] = imv[j] + dv;
                accdb += dv * dv;
            }
        }
    }
    float obS[4] = {0.f,0.f,0.f,0.f};
    if (ty == 15 && hasS) {
        uint32_t ssh = __shfl_up(paS[3], 1, 64);
        uint32_t sl = (tx > 0) ? ssh : paSW;
        float im1[4]; h4_to_f(ihS1, im1);
        #pragma unroll
        for (int j = 0; j < 4; ++j) {
            float2 cf = h2f(paS[j]);
            float up = h2f(pa[3][j]).x;
            float le = (j > 0) ? h2f(paS[j - 1]).y : h2f(sl).y;
            obS[j] = im1[j] + (-(cf.x + cf.y) + up + le);
        }
    }
    float obE[4] = {0.f,0.f,0.f,0.f};
    if (tx == 15 && hasE) {
        #pragma unroll
        for (int i = 0; i < 4; ++i) {
            float2 cf = h2f(paE[i]);
            float up = (i > 0) ? h2f(paE[i - 1]).x
                               : ((ty > 0) ? h2f(EP[ty - 1]).x : h2f(paNE).x);
            float le = h2f(pa[i][3]).y;
            obE[i] = ihE1[i] + (-(cf.x + cf.y) + up + le);
        }
    }
    OB[ty][tx] = make_float4(ob[0][0], ob[0][1], ob[0][2], ob[0][3]);
    __syncthreads();  // s4: OB (out_b bands)

    // ================= PT_B + store =================
    float accnb = 0.f;
    {
        float bel4[4];
        if (ty < 15) {
            float4 t = OB[ty + 1][tx];
            bel4[0] = t.x; bel4[1] = t.y; bel4[2] = t.z; bel4[3] = t.w;
        } else {
            bel4[0] = obS[0]; bel4[1] = obS[1]; bel4[2] = obS[2]; bel4[3] = obS[3];
        }
        #pragma unroll
        for (int i = 0; i < 4; ++i) {
            int gy = gy0 + i;
            float rsh = __shfl_down(ob[i][0], 1, 64);
            float rt = (tx < 15) ? rsh : obE[i];
            uint32_t pv[4];
            #pragma unroll
            for (int j = 0; j < 4; ++j) {
                float ov = ob[i][j];
                float bel = (i < 3) ? ob[i + 1][j] : bel4[j];
                float g0 = (gy < HH - 1) ? bel - ov : 0.f;
                float rn = (j < 3) ? ob[i][j + 1] : rt;
                float g1 = (gx + j < WW - 1) ? rn - ov : 0.f;
                float ss2 = g0 * g0 + g1 * g1;
                float nrm = (ss2 > 0.f) ? sqrtf(ss2) : 0.f;
                accnb += nrm;
                float inv = __builtin_amdgcn_rcpf(1.f + tw * nrm);
                float2 cf = h2f(pa[i][j]);
                pv[j] = f2h2((cf.x - TAU * g0) * inv, (cf.y - TAU * g1) * inv);
            }
            *(uint4*)(poutI + (size_t)gy * WW + gx) = make_uint4(pv[0], pv[1], pv[2], pv[3]);
        }
    }
    const int sOut = m & 1;
    red4_store(accda, accna, accdb, accnb,
               &sums[SUMIX(sOut, 0, im) + bid], &sums[SUMIX(sOut, 1, im) + bid],
               &sums[SUMIX(sOut, 2, im) + bid], &sums[SUMIX(sOut, 3, im) + bid], tid);
}

// =========================== epilogue (round-2 verified) ===========================
__global__ __launch_bounds__(256, 3) void tv_out(
    const float* __restrict__ img, float* __restrict__ out,
    const uint32_t* __restrict__ ptA, const uint32_t* __restrict__ ptB,
    const __half* __restrict__ imgh, const float* __restrict__ weight,
    const float* __restrict__ sc, const float* __restrict__ sums)
{
    const int im = blockIdx.z;
    const int tid = threadIdx.x;
    const float w = weight[im / CCH];

    __shared__ int2 shk;
    {
        const float* sI = sc;  // slot 0 = S_6 (written by m=4)
        int done = ((const int*)sI)[64 + im];
        int lastk = ((const int*)sI)[96 + im];
        if (!done && tid < 64) {
            float da = sums[SUMIX(0, 0, im) + tid];
            float na = sums[SUMIX(0, 1, im) + tid];
            float db = sums[SUMIX(0, 2, im) + tid];
            float nb = sums[SUMIX(0, 3, im) + tid];
            for (int off = 32; off > 0; off >>= 1) {
                da += __shfl_down(da, off, 64);
                na += __shfl_down(na, off, 64);
                db += __shfl_down(db, off, 64);
                nb += __shfl_down(nb, off, 64);
            }
            if (tid == 0) {
                float Eprev = sI[im], Einit = sI[32 + im];
                float Et = (da + w * na) / NUMEL;                  // iter 7
                if (fabsf(Eprev - Et) < TVEPS * Einit) { done = 1; lastk = 7; }
                else {
                    Eprev = Et;
                    Et = (db + w * nb) / NUMEL;                    // iter 8
                    if (fabsf(Eprev - Et) < TVEPS * Einit) { done = 1; lastk = 8; }
                }
            }
        }
        if (tid == 0) { shk.x = done; shk.y = lastk; }
    }
    __syncthreads();
    const int k = shk.x ? shk.y : 9;

    const float* imgI = img + (size_t)im * HH * WW;
    float* outI = out + (size_t)im * HH * WW;
    const int x0 = blockIdx.x * 64, y0 = blockIdx.y * 64;
    const int tx = tid & 15, ry = tid >> 4;
    const int gx = x0 + 4 * tx;

    if (k & 1) {
        // k in {1,3,5,7,9}: pt_{k-1} materialized. pt_0:A pt_2:B pt_4:A pt_6:B pt_8:A
        const uint32_t* p = ((((k - 1) >> 1) & 1) ? ptB : ptA) + (size_t)im * HH * WW;
        #pragma unroll
        for (int i = 0; i < 4; ++i) {
            int gy = y0 + ry + 16 * i;
            size_t off = (size_t)gy * WW + gx;
            uint4 cv = *(const uint4*)(p + off);
            uint4 uv = make_uint4(0u, 0u, 0u, 0u);
            if (gy > 0) uv = *(const uint4*)(p + off - WW);
            uint32_t lf = (gx > 0) ? p[off - 1] : 0u;
            float4 iv = *(const float4*)(imgI + off);
            uint32_t cc[4] = {cv.x, cv.y, cv.z, cv.w};
            uint32_t uu[4] = {uv.x, uv.y, uv.z, uv.w};
            uint32_t lt[4] = {lf, cv.x, cv.y, cv.z};
            float ivv[4] = {iv.x, iv.y, iv.z, iv.w};
            float r[4];
            #pragma unroll
            for (int j = 0; j < 4; ++j) {
                float2 cf = h2f(cc[j]);
                r[j] = ivv[j] + (-(cf.x + cf.y) + h2f(uu[j]).x + h2f(lt[j]).y);
            }
            *(float4*)(outI + off) = make_float4(r[0], r[1], r[2], r[3]);
        }
    } else {
        // k in {2,4,6,8}: recompute pt_{k-1} from preserved pt_{k-2}.
        const uint32_t* p = ((((k - 2) >> 1) & 1) ? ptB : ptA) + (size_t)im * HH * WW;
        const __half* hI = imgh + (size_t)im * HH * WW;
        const float tw = TAU / w;
        __shared__ Smem S;
        stage_pt_im(S, p, hI, x0, y0, tid);
        __syncthreads();
        phase_outA_x(S, tid);
        __syncthreads();
        phase_ptA_x(S, x0, y0, tid, tw);
        __syncthreads();
        #pragma unroll
        for (int i = 0; i < 4; ++i) {
            int gy = y0 + ry + 16 * i;
            int r = 2 + ry + 16 * i;
            size_t off = (size_t)gy * WW + gx;
            float4 iv = *(const float4*)(imgI + off);
            float ivv[4] = {iv.x, iv.y, iv.z, iv.w};
            float rr[4];
            #pragma unroll
            for (int j = 0; j < 4; ++j) {
                int cix = 2 + 4 * tx + j;
                float2 cf = h2f(S.PT[r * LSF + cix]);
                float up = h2f(S.PT[(r - 1) * LSF + cix]).x;
                float lf = h2f(S.PT[r * LSF + cix - 1]).y;
                rr[j] = ivv[j] + (-(cf.x + cf.y) + up + lf);
            }
            *(float4*)(outI + off) = make_float4(rr[0], rr[1], rr[2], rr[3]);
        }
    }
}

extern "C" void kernel_launch(void* const* d_in, const int* in_sizes, int n_in,
                              void* d_out, int out_size, void* d_ws, size_t ws_size,
                              hipStream_t stream)
{
    const float* img = (const float*)d_in[0];
    const float* weight = (const float*)d_in[1];
    float* out = (float*)d_out;
    float* sc = (float*)d_ws;
    float* sums = (float*)((char*)d_ws + 4096);
    __half* imgh = (__half*)((char*)d_ws + 65536);
    uint32_t* ptA = (uint32_t*)((char*)d_ws + 12648448);
    uint32_t* ptB = (uint32_t*)((char*)d_ws + 37814272);

    dim3 grid(8, 8, NIMG);
    dim3 block(256);

    // iteration 0 -> pt_0 in A; accn into sums slot0/arr1
    tv_step0<<<grid, block, 0, stream>>>(img, weight, imgh, ptA,
                                         sums + (0 * 4 + 1) * NIMG * 64);

    // fused pairs m=1..4 cover iterations 1..8; m odd A->B, m even B->A
    for (int m = 1; m <= 4; ++m) {
        uint32_t* pin  = (m & 1) ? ptA : ptB;
        uint32_t* pout = (m & 1) ? ptB : ptA;
        tv_fused<<<grid, block, 0, stream>>>(m, imgh, weight, pin, pout, sc, sums);
    }

    // iteration 9's pt is dead; epilogue replays iters 7,8 and emits out.
    tv_out<<<grid, block, 0, stream>>>(img, out, ptA, ptB, imgh, weight, sc, sums);
}